// Round 1
// baseline (6715.285 us; speedup 1.0000x reference)
//
#include <hip/hip_runtime.h>

// PatchDecoder: trilinear interp from 64^3 x 32 grid + 5-block ResNet MLP (HID=128).
// Round 1: fp32 correctness-first tiled kernel.
//   - TQ=32 queries per 256-thread block (500000 = 32 * 15625, no tail in practice,
//     but guarded anyway).
//   - Activations in LDS (net/h: [32][132] fp32, lat: [32][32]).
//   - Weights streamed per 64-wide K chunk into LDS ([128][68] fp32).
//   - Each thread owns a 4q x 4j output tile; X reads are lane-broadcast,
//     W reads ~4-way bank conflict (stride 68 -> 4*l mod 32).
// LDS total ~72 KB -> 2 blocks/CU, 8 waves/CU.

#define TQ 32
#define BLOCK 256
#define HD 128
#define ZD 32
#define NBLK 5
#define GR 64
#define XSTR 132
#define WSTR 68

struct SMem {
  float net[TQ][XSTR];
  float hbuf[TQ][XSTR];
  float lat[TQ][ZD];
  float w[HD][WSTR];
  float partial[TQ][8];
};

template <int KTOT, int XS, bool RELU, bool ACCUM>
__device__ __forceinline__ void mlp_matmul(SMem* sm, const float* __restrict__ X,
                                           const float* __restrict__ Wg,
                                           const float* __restrict__ bg,
                                           float* __restrict__ Y, int t) {
  constexpr int CH = (KTOT >= 64) ? 64 : KTOT;   // K chunk staged in LDS
  constexpr int NCH = KTOT / CH;
  constexpr int ROWF4 = CH / 4;                  // float4s per weight row chunk
  constexpr int NF4 = HD * ROWF4;                // float4s per chunk
  constexpr int NSTAGE = NF4 / BLOCK;            // staging iters per thread

  const int lane_j = t & 31;        // j base (strided by 32)
  const int q0 = (t >> 5) << 2;     // 4 consecutive queries

  float acc[4][4];
#pragma unroll
  for (int a = 0; a < 4; ++a)
#pragma unroll
    for (int b = 0; b < 4; ++b) acc[a][b] = 0.f;

#pragma unroll
  for (int c = 0; c < NCH; ++c) {
    const int kc = c * CH;
    __syncthreads();  // prior readers of sm->w / writers of X are done
#pragma unroll
    for (int r = 0; r < NSTAGE; ++r) {
      const int e = t + r * BLOCK;
      const int row = e / ROWF4;
      const int c4 = (e % ROWF4) * 4;
      *(float4*)&sm->w[row][c4] = *(const float4*)&Wg[row * KTOT + kc + c4];
    }
    __syncthreads();
#pragma unroll
    for (int k = 0; k < CH; k += 4) {
      float4 xv[4], wv[4];
#pragma unroll
      for (int qq = 0; qq < 4; ++qq)
        xv[qq] = *(const float4*)&X[(q0 + qq) * XS + kc + k];
#pragma unroll
      for (int jj = 0; jj < 4; ++jj)
        wv[jj] = *(const float4*)&sm->w[lane_j + 32 * jj][k];
      if (RELU) {
#pragma unroll
        for (int qq = 0; qq < 4; ++qq) {
          xv[qq].x = fmaxf(xv[qq].x, 0.f);
          xv[qq].y = fmaxf(xv[qq].y, 0.f);
          xv[qq].z = fmaxf(xv[qq].z, 0.f);
          xv[qq].w = fmaxf(xv[qq].w, 0.f);
        }
      }
#pragma unroll
      for (int qq = 0; qq < 4; ++qq)
#pragma unroll
        for (int jj = 0; jj < 4; ++jj) {
          acc[qq][jj] = fmaf(xv[qq].x, wv[jj].x, acc[qq][jj]);
          acc[qq][jj] = fmaf(xv[qq].y, wv[jj].y, acc[qq][jj]);
          acc[qq][jj] = fmaf(xv[qq].z, wv[jj].z, acc[qq][jj]);
          acc[qq][jj] = fmaf(xv[qq].w, wv[jj].w, acc[qq][jj]);
        }
    }
  }
  __syncthreads();  // all reads of X / sm->w done before Y is written
#pragma unroll
  for (int qq = 0; qq < 4; ++qq)
#pragma unroll
    for (int jj = 0; jj < 4; ++jj) {
      const int j = lane_j + 32 * jj;
      const float v = acc[qq][jj] + bg[j];
      if (ACCUM)
        Y[(q0 + qq) * XSTR + j] += v;
      else
        Y[(q0 + qq) * XSTR + j] = v;
    }
}

__global__ __launch_bounds__(BLOCK, 2) void patch_decoder_kernel(
    const float* __restrict__ z_feats, const float* __restrict__ query,
    const float* __restrict__ fc_p_w, const float* __restrict__ fc_p_b,
    const float* __restrict__ fc_c_w, const float* __restrict__ fc_c_b,
    const float* __restrict__ fc0_w, const float* __restrict__ fc0_b,
    const float* __restrict__ fc1_w, const float* __restrict__ fc1_b,
    const float* __restrict__ fc_out_w, const float* __restrict__ fc_out_b,
    float* __restrict__ out, int nq) {
  __shared__ SMem sm;
  const int t = threadIdx.x;
  const int qbase = blockIdx.x * TQ;

  // ---- trilinear interpolation: 8 threads per query, 4 features each ----
  {
    const int q = t >> 3;          // 0..31
    const int fg = (t & 7) * 4;    // feature base
    const int qg = qbase + q;
    float4 acc = make_float4(0.f, 0.f, 0.f, 0.f);
    if (qg < nq) {
      const float qx = query[qg * 3 + 0];
      const float qy = query[qg * 3 + 1];
      const float qz = query[qg * 3 + 2];
      const float fx = floorf(qx), fy = floorf(qy), fz = floorf(qz);
      const float rx = qx - fx, ry = qy - fy, rz = qz - fz;
      const int bx = (int)fx, by = (int)fy, bz = (int)fz;
#pragma unroll
      for (int c = 0; c < 8; ++c) {
        const int ox = (c >> 2) & 1, oy = (c >> 1) & 1, oz = c & 1;
        const float w =
            (ox ? rx : 1.f - rx) * (oy ? ry : 1.f - ry) * (oz ? rz : 1.f - rz);
        const int flat = ((bx + ox) * GR + (by + oy)) * GR + (bz + oz);
        const float4 v = *(const float4*)&z_feats[(size_t)flat * ZD + fg];
        acc.x = fmaf(w, v.x, acc.x);
        acc.y = fmaf(w, v.y, acc.y);
        acc.z = fmaf(w, v.z, acc.z);
        acc.w = fmaf(w, v.w, acc.w);
      }
    }
    *(float4*)&sm.lat[q][fg] = acc;
  }
  // visibility of sm.lat is guaranteed by the double sync at the head of the
  // first mlp_matmul chunk, but keep one explicit sync for clarity:
  __syncthreads();

  // ---- decoder ----
  // net = lat @ fc_p_w.T + fc_p_b
  mlp_matmul<ZD, ZD, false, false>(&sm, &sm.lat[0][0], fc_p_w, fc_p_b,
                                   &sm.net[0][0], t);
#pragma unroll 1
  for (int i = 0; i < NBLK; ++i) {
    // net += lat @ fc_c_w[i].T + fc_c_b[i]
    mlp_matmul<ZD, ZD, false, true>(&sm, &sm.lat[0][0], fc_c_w + i * HD * ZD,
                                    fc_c_b + i * HD, &sm.net[0][0], t);
    // h = relu(net) @ fc0_w[i].T + fc0_b[i]
    mlp_matmul<HD, XSTR, true, false>(&sm, &sm.net[0][0], fc0_w + i * HD * HD,
                                      fc0_b + i * HD, &sm.hbuf[0][0], t);
    // net += relu(h) @ fc1_w[i].T + fc1_b[i]
    mlp_matmul<HD, XSTR, true, true>(&sm, &sm.hbuf[0][0], fc1_w + i * HD * HD,
                                     fc1_b + i * HD, &sm.net[0][0], t);
  }
  __syncthreads();

  // ---- output: out[q] = leaky_relu(net[q], 0.2) . fc_out_w + fc_out_b ----
  {
    const int q = t >> 3;
    const int jp = t & 7;
    const int k0 = jp * 16;
    float s = 0.f;
#pragma unroll
    for (int k = 0; k < 16; ++k) {
      float v = sm.net[q][k0 + k];
      v = (v > 0.f) ? v : 0.2f * v;
      s = fmaf(v, fc_out_w[k0 + k], s);
    }
    sm.partial[q][jp] = s;
  }
  __syncthreads();
  if ((t & 7) == 0) {
    const int q = t >> 3;
    if (qbase + q < nq) {
      float r = fc_out_b[0];
#pragma unroll
      for (int i = 0; i < 8; ++i) r += sm.partial[q][i];
      out[qbase + q] = r;
    }
  }
}

extern "C" void kernel_launch(void* const* d_in, const int* in_sizes, int n_in,
                              void* d_out, int out_size, void* d_ws,
                              size_t ws_size, hipStream_t stream) {
  const float* z_feats = (const float*)d_in[0];
  const float* query = (const float*)d_in[1];
  const float* fc_p_w = (const float*)d_in[2];
  const float* fc_p_b = (const float*)d_in[3];
  const float* fc_c_w = (const float*)d_in[4];
  const float* fc_c_b = (const float*)d_in[5];
  const float* fc0_w = (const float*)d_in[6];
  const float* fc0_b = (const float*)d_in[7];
  const float* fc1_w = (const float*)d_in[8];
  const float* fc1_b = (const float*)d_in[9];
  const float* fc_out_w = (const float*)d_in[10];
  const float* fc_out_b = (const float*)d_in[11];
  float* out = (float*)d_out;

  const int nq = in_sizes[1] / 3;
  const int grid = (nq + TQ - 1) / TQ;
  patch_decoder_kernel<<<grid, BLOCK, 0, stream>>>(
      z_feats, query, fc_p_w, fc_p_b, fc_c_w, fc_c_b, fc0_w, fc0_b, fc1_w,
      fc1_b, fc_out_w, fc_out_b, out, nq);
}

// Round 2
// 552.238 us; speedup vs baseline: 12.1601x; 12.1601x over previous
//
#include <hip/hip_runtime.h>

// PatchDecoder round 2: fp16 MFMA (v_mfma_f32_16x16x32_f16), fp32 accum.
//
// Kernel 1 (convert_weights): fp32 weights -> fp16 into d_ws.
//   fc0/fc1 stored PRE-SWIZZLED (16B granule cg holds logical granule
//   cg ^ (row&7)) so the main kernel stages LDS linearly (coalesced) and
//   frag ds_read_b128 is 2-way-max on banks (T2-style XOR swizzle).
// Kernel 2 (main): per block TQ=128 queries, 512 threads = 8 waves.
//   wave w: j-half = w&1 (64 outs, 4 j-tiles), q-quarter = w>>1 (32 q, 2 tiles).
//   Per layer: W frags register-persistent (16 x half8 = 64 VGPR), activations
//   fp16 in swizzled LDS, acc f32x4 initialized with bias.
//   MFMA: A = W (M=j), B = act^T (N=q); D: col=lane&15 (q), row=4*(lane>>4)+r (j).
// LDS ~107KB -> 1 block/CU, 2 waves/SIMD.

#define TQ 128
#define BLOCK 512
#define HD 128
#define ZD 32
#define NBLK 5
#define GR 64

typedef _Float16 f16x8 __attribute__((ext_vector_type(8)));
typedef _Float16 f16x4 __attribute__((ext_vector_type(4)));
typedef float f32x4 __attribute__((ext_vector_type(4)));

// ws layout in halves
#define OFF_P 0            // fc_p_w  [128][32] packed          (4096)
#define OFF_C 4096         // fc_c_w  [5][128][32] packed       (20480)
#define OFF_0 24576        // fc0_w   [5][128][128] swizzled    (81920)
#define OFF_1 106496       // fc1_w   [5][128][128] swizzled    (81920)
#define WS_HALVES 188416

__global__ void convert_weights(const float* __restrict__ fc_p_w,
                                const float* __restrict__ fc_c_w,
                                const float* __restrict__ fc0_w,
                                const float* __restrict__ fc1_w,
                                _Float16* __restrict__ ws) {
  int i = blockIdx.x * 256 + threadIdx.x;
  if (i >= WS_HALVES) return;
  if (i < 4096) {
    ws[OFF_P + i] = (_Float16)fc_p_w[i];
    return;
  }
  i -= 4096;
  if (i < 20480) {
    ws[OFF_C + i] = (_Float16)fc_c_w[i];
    return;
  }
  i -= 20480;
  if (i < 81920) {
    const int row = i >> 7;        // 0..639 (row%128 matters only &7)
    const int col = i & 127;
    const int cg = col >> 3, e = col & 7;
    const int scol = (((cg ^ (row & 7)) << 3) | e);
    ws[OFF_0 + i] = (_Float16)fc0_w[(row << 7) + scol];
    return;
  }
  i -= 81920;
  {
    const int row = i >> 7;
    const int col = i & 127;
    const int cg = col >> 3, e = col & 7;
    const int scol = (((cg ^ (row & 7)) << 3) | e);
    ws[OFF_1 + i] = (_Float16)fc1_w[(row << 7) + scol];
  }
}

struct SMem {
  _Float16 net[TQ * HD];     // swizzled granules, 32KB
  _Float16 hbuf[TQ * HD];    // swizzled, 32KB; head reused as lat scratch [128][40]
  _Float16 wbig[HD * HD];    // swizzled, 32KB
  _Float16 wsmall[HD * 40];  // padded rows (80B), 10KB
  float biasA[HD];           // fc_p / fc_c bias
  float biasB[HD];           // fc0 / fc1 bias
};

__device__ __forceinline__ f16x8 read_swz(const _Float16* buf, int row, int g) {
  return *(const f16x8*)((const char*)buf + row * 256 + (((g ^ (row & 7)) << 4)));
}

__device__ __forceinline__ f16x8 relu8(f16x8 v) {
  f16x8 z;
#pragma unroll
  for (int e = 0; e < 8; ++e) z[e] = (_Float16)0.0f;
  return __builtin_elementwise_max(v, z);
}

// epilogue: store or RMW 4 consecutive j (half4) at dst[q][jb..jb+3], swizzled
template <bool RMW>
__device__ __forceinline__ void epi_write(_Float16* dst, int q, int jb,
                                          const f32x4& a) {
  char* p = (char*)dst + q * 256 + ((((jb >> 3) ^ (q & 7)) << 4) | ((jb & 7) << 1));
  f16x4 hv;
  if (RMW) {
    f16x4 old = *(const f16x4*)p;
#pragma unroll
    for (int r = 0; r < 4; ++r) hv[r] = (_Float16)(a[r] + (float)old[r]);
  } else {
#pragma unroll
    for (int r = 0; r < 4; ++r) hv[r] = (_Float16)a[r];
  }
  *(f16x4*)p = hv;
}

template <bool RELU, bool RMW>
__device__ __forceinline__ void big_layer(const _Float16* src, _Float16* dst,
                                          const f16x8* wf, const f32x4* bv,
                                          int q0w, int j0, int lr, int lg) {
#pragma unroll
  for (int qt = 0; qt < 2; ++qt) {
    const int q = q0w + qt * 16 + lr;
    f16x8 xf[4];
#pragma unroll
    for (int ks = 0; ks < 4; ++ks) {
      xf[ks] = read_swz(src, q, ks * 4 + lg);
      if (RELU) xf[ks] = relu8(xf[ks]);
    }
    f32x4 acc[4];
#pragma unroll
    for (int jt = 0; jt < 4; ++jt) acc[jt] = bv[jt];
#pragma unroll
    for (int ks = 0; ks < 4; ++ks)
#pragma unroll
      for (int jt = 0; jt < 4; ++jt)
        acc[jt] = __builtin_amdgcn_mfma_f32_16x16x32_f16(wf[jt * 4 + ks], xf[ks],
                                                         acc[jt], 0, 0, 0);
#pragma unroll
    for (int jt = 0; jt < 4; ++jt)
      epi_write<RMW>(dst, q, j0 + jt * 16 + (lg << 2), acc[jt]);
  }
}

template <bool RMW>
__device__ __forceinline__ void small_layer(_Float16* dst, const f16x8* wf,
                                            const f16x8* latf, const f32x4* bv,
                                            int q0w, int j0, int lr, int lg) {
#pragma unroll
  for (int qt = 0; qt < 2; ++qt) {
    const int q = q0w + qt * 16 + lr;
    f32x4 acc[4];
#pragma unroll
    for (int jt = 0; jt < 4; ++jt) acc[jt] = bv[jt];
#pragma unroll
    for (int jt = 0; jt < 4; ++jt)
      acc[jt] = __builtin_amdgcn_mfma_f32_16x16x32_f16(wf[jt], latf[qt], acc[jt],
                                                       0, 0, 0);
#pragma unroll
    for (int jt = 0; jt < 4; ++jt)
      epi_write<RMW>(dst, q, j0 + jt * 16 + (lg << 2), acc[jt]);
  }
}

__global__ __launch_bounds__(BLOCK, 2) void patch_decoder_kernel(
    const float* __restrict__ z_feats, const float* __restrict__ query,
    const _Float16* __restrict__ ws, const float* __restrict__ fc_p_b,
    const float* __restrict__ fc_c_b, const float* __restrict__ fc0_b,
    const float* __restrict__ fc1_b, const float* __restrict__ fc_out_w,
    const float* __restrict__ fc_out_b, float* __restrict__ out, int nq) {
  __shared__ SMem sm;
  const int t = threadIdx.x;
  const int w = t >> 6;
  const int l = t & 63;
  const int lr = l & 15, lg = l >> 4;
  const int j0 = (w & 1) << 6;     // j-half base
  const int q0w = (w >> 1) << 5;   // q-quarter base
  const int qbase = blockIdx.x * TQ;

  // ---- phase 0: interpolation -> lat scratch (in hbuf region, rows 80B) ----
  {
    const int q = t >> 2, s = t & 3;
    const int qg = qbase + q;
    float acc[8];
#pragma unroll
    for (int e = 0; e < 8; ++e) acc[e] = 0.f;
    if (qg < nq) {
      const float qx = query[qg * 3 + 0];
      const float qy = query[qg * 3 + 1];
      const float qz = query[qg * 3 + 2];
      const float fx = floorf(qx), fy = floorf(qy), fz = floorf(qz);
      const float rx = qx - fx, ry = qy - fy, rz = qz - fz;
      const int bx = (int)fx, by = (int)fy, bz = (int)fz;
      const float wx[2] = {1.f - rx, rx}, wy[2] = {1.f - ry, ry},
                  wz[2] = {1.f - rz, rz};
#pragma unroll
      for (int c = 0; c < 8; ++c) {
        const int ox = (c >> 2) & 1, oy = (c >> 1) & 1, oz = c & 1;
        const float wgt = wx[ox] * wy[oy] * wz[oz];
        const float* f =
            z_feats + (size_t)(((bx + ox) * GR + (by + oy)) * GR + (bz + oz)) * ZD +
            s * 8;
        const float4 v0 = *(const float4*)f;
        const float4 v1 = *(const float4*)(f + 4);
        acc[0] = fmaf(wgt, v0.x, acc[0]);
        acc[1] = fmaf(wgt, v0.y, acc[1]);
        acc[2] = fmaf(wgt, v0.z, acc[2]);
        acc[3] = fmaf(wgt, v0.w, acc[3]);
        acc[4] = fmaf(wgt, v1.x, acc[4]);
        acc[5] = fmaf(wgt, v1.y, acc[5]);
        acc[6] = fmaf(wgt, v1.z, acc[6]);
        acc[7] = fmaf(wgt, v1.w, acc[7]);
      }
    }
    f16x8 hv;
#pragma unroll
    for (int e = 0; e < 8; ++e) hv[e] = (_Float16)acc[e];
    *(f16x8*)((char*)sm.hbuf + q * 80 + s * 16) = hv;
  }
  // stage wsmall = fc_p_w (packed [128][32]) + biasA = fc_p_b
  {
    const int row = t >> 2, g = t & 3;
    *(uint4*)((char*)sm.wsmall + row * 80 + g * 16) =
        *(const uint4*)((const char*)(ws + OFF_P) + (row * 32 + g * 8) * 2);
    if (t < HD) sm.biasA[t] = fc_p_b[t];
  }
  __syncthreads();  // B1

  // lat frags (persist whole kernel): lane holds lat[q0w+qt*16+lr][8*lg+e]
  f16x8 latf[2];
#pragma unroll
  for (int qt = 0; qt < 2; ++qt) {
    const int row = q0w + qt * 16 + lr;
    latf[qt] = *(const f16x8*)((const char*)sm.hbuf + row * 80 + lg * 16);
  }

  // ---- fc_p: net = lat @ Wp^T + bp ----
  {
    f16x8 wf[4];
#pragma unroll
    for (int jt = 0; jt < 4; ++jt) {
      const int row = j0 + jt * 16 + lr;
      wf[jt] = *(const f16x8*)((const char*)sm.wsmall + row * 80 + lg * 16);
    }
    f32x4 bv[4];
#pragma unroll
    for (int jt = 0; jt < 4; ++jt)
      bv[jt] = *(const f32x4*)&sm.biasA[j0 + jt * 16 + (lg << 2)];
    small_layer<false>(sm.net, wf, latf, bv, q0w, j0, lr, lg);
  }
  __syncthreads();  // B2: net stored, wsmall frag reads done

#pragma unroll 1
  for (int i = 0; i < NBLK; ++i) {
    // stage wsmall = fc_c_w[i], biasA = fc_c_b[i]; wbig = fc0_w[i], biasB = fc0_b[i]
    {
      const int row = t >> 2, g = t & 3;
      *(uint4*)((char*)sm.wsmall + row * 80 + g * 16) =
          *(const uint4*)((const char*)(ws + OFF_C + i * 4096) +
                          (row * 32 + g * 8) * 2);
      const char* wsrc = (const char*)(ws + OFF_0 + i * 16384);
#pragma unroll
      for (int r = 0; r < 4; ++r) {
        const int idx = r * BLOCK + t;
        *(uint4*)((char*)sm.wbig + idx * 16) = *(const uint4*)(wsrc + idx * 16);
      }
      if (t < HD) sm.biasA[t] = fc_c_b[i * HD + t];
      else if (t < 2 * HD) sm.biasB[t - HD] = fc0_b[i * HD + (t - HD)];
    }
    __syncthreads();  // B3

    // fc_c: net += lat @ Wc^T + bc
    {
      f16x8 wf[4];
#pragma unroll
      for (int jt = 0; jt < 4; ++jt) {
        const int row = j0 + jt * 16 + lr;
        wf[jt] = *(const f16x8*)((const char*)sm.wsmall + row * 80 + lg * 16);
      }
      f32x4 bv[4];
#pragma unroll
      for (int jt = 0; jt < 4; ++jt)
        bv[jt] = *(const f32x4*)&sm.biasA[j0 + jt * 16 + (lg << 2)];
      small_layer<true>(sm.net, wf, latf, bv, q0w, j0, lr, lg);
    }
    // preload fc0 W-frags + bias (wbig staged at B3)
    f16x8 wf0[16];
#pragma unroll
    for (int jt = 0; jt < 4; ++jt)
#pragma unroll
      for (int ks = 0; ks < 4; ++ks)
        wf0[jt * 4 + ks] = read_swz(sm.wbig, j0 + jt * 16 + lr, ks * 4 + lg);
    f32x4 bv0[4];
#pragma unroll
    for (int jt = 0; jt < 4; ++jt)
      bv0[jt] = *(const f32x4*)&sm.biasB[j0 + jt * 16 + (lg << 2)];
    __syncthreads();  // B4: net complete across waves; wbig frag reads done

    // fc0: h = relu(net) @ W0^T + b0
    big_layer<true, false>(sm.net, sm.hbuf, wf0, bv0, q0w, j0, lr, lg);
    __syncthreads();  // B5: h complete; wbig free

    // stage wbig = fc1_w[i], biasB = fc1_b[i]
    {
      const char* wsrc = (const char*)(ws + OFF_1 + i * 16384);
#pragma unroll
      for (int r = 0; r < 4; ++r) {
        const int idx = r * BLOCK + t;
        *(uint4*)((char*)sm.wbig + idx * 16) = *(const uint4*)(wsrc + idx * 16);
      }
      if (t < HD) sm.biasB[t] = fc1_b[i * HD + t];
    }
    __syncthreads();  // B6

    // fc1: net += relu(h) @ W1^T + b1
    {
      f16x8 wf1[16];
#pragma unroll
      for (int jt = 0; jt < 4; ++jt)
#pragma unroll
        for (int ks = 0; ks < 4; ++ks)
          wf1[jt * 4 + ks] = read_swz(sm.wbig, j0 + jt * 16 + lr, ks * 4 + lg);
      f32x4 bv1[4];
#pragma unroll
      for (int jt = 0; jt < 4; ++jt)
        bv1[jt] = *(const f32x4*)&sm.biasB[j0 + jt * 16 + (lg << 2)];
      big_layer<true, true>(sm.hbuf, sm.net, wf1, bv1, q0w, j0, lr, lg);
    }
    __syncthreads();  // B7: net complete; wbig/wsmall frag reads done
  }

  // ---- output: out[q] = leaky_relu(net[q], 0.2) . fc_out_w + fc_out_b ----
  {
    const int q = t >> 2, s = t & 3;
    const int qg = qbase + q;
    float sum = 0.f;
#pragma unroll
    for (int gi = 0; gi < 4; ++gi) {
      const int g = s * 4 + gi;
      const f16x8 v =
          *(const f16x8*)((const char*)sm.net + q * 256 + ((g ^ (q & 7)) << 4));
      const float* wp = fc_out_w + g * 8;
#pragma unroll
      for (int e = 0; e < 8; ++e) {
        float x = (float)v[e];
        x = (x > 0.f) ? x : 0.2f * x;
        sum = fmaf(x, wp[e], sum);
      }
    }
    sum += __shfl_xor(sum, 1);
    sum += __shfl_xor(sum, 2);
    if (s == 0 && qg < nq) out[qg] = sum + fc_out_b[0];
  }
}

extern "C" void kernel_launch(void* const* d_in, const int* in_sizes, int n_in,
                              void* d_out, int out_size, void* d_ws,
                              size_t ws_size, hipStream_t stream) {
  const float* z_feats = (const float*)d_in[0];
  const float* query = (const float*)d_in[1];
  const float* fc_p_w = (const float*)d_in[2];
  const float* fc_p_b = (const float*)d_in[3];
  const float* fc_c_w = (const float*)d_in[4];
  const float* fc_c_b = (const float*)d_in[5];
  const float* fc0_w = (const float*)d_in[6];
  const float* fc0_b = (const float*)d_in[7];
  const float* fc1_w = (const float*)d_in[8];
  const float* fc1_b = (const float*)d_in[9];
  const float* fc_out_w = (const float*)d_in[10];
  const float* fc_out_b = (const float*)d_in[11];
  float* out = (float*)d_out;
  _Float16* ws = (_Float16*)d_ws;

  const int nq = in_sizes[1] / 3;

  convert_weights<<<(WS_HALVES + 255) / 256, 256, 0, stream>>>(
      fc_p_w, fc_c_w, fc0_w, fc1_w, ws);

  const int grid = (nq + TQ - 1) / TQ;
  patch_decoder_kernel<<<grid, BLOCK, 0, stream>>>(
      z_feats, query, ws, fc_p_b, fc_c_b, fc0_b, fc1_b, fc_out_w, fc_out_b, out,
      nq);
}

// Round 3
// 460.687 us; speedup vs baseline: 14.5767x; 1.1987x over previous
//
#include <hip/hip_runtime.h>

// PatchDecoder round 3: fp16 MFMA, TQ=256, k-split hidden layer, async
// reg-staged weight prefetch, f32 register-resident net accumulator.
//
// Weights converted to fp16 in d_ws (pre-XOR-swizzled for LDS-staged chunks):
//   Wp [128][32] linear, Wc [5][128][32] linear (frags read DIRECT from global),
//   W0 [5][2 jhalf][64][128] swizzled chunks (16KB each),
//   W1 [5][2 khalf][128][64] swizzled chunks (16KB each).
//
// Main kernel: 512 thr = 8 waves, TQ=256 queries.
//   Main partition: wave w -> j-half (w&1), q-quarter (w>>1): acc[4jt][4qt] f32x4.
//   fc0 phases partition by q-eighth (w*32), all 64 j of the current half.
//   Per iter: P0 fc_c + NET(relu,fp16,swz) | P1 h0=NET@W0h0 -> H | P2 dx+=H@W1k0
//             | P3 h1 -> H | P4 dx+=H@W1k1 (+bias). 4 barriers/iter.
//   Chunk pipeline: slots {0:W0h0,1:W1k0,2:W0h1}, C3(W1k1)->slot0 mid-iter.
//   Next-iter loads issued at P2 start (regs), ds_written at next P0/P2.
// LDS: NET 64KB + H 32KB (aliases gather lat, epilogue reduce) + 3x16KB = 144KB.

#define TQ 256
#define BLOCK 512
#define HD 128
#define ZD 32
#define NBLK 5
#define GR 64

typedef _Float16 f16x8 __attribute__((ext_vector_type(8)));
typedef _Float16 f16x4 __attribute__((ext_vector_type(4)));
typedef float f32x4 __attribute__((ext_vector_type(4)));

// d_ws layout in halves
#define OFF_P 0            // fc_p_w [128][32]                  (4096)
#define OFF_C 4096         // fc_c_w [5][128][32]               (20480)
#define OFF_0 24576        // fc0_w  [5][2][64][128] swizzled   (81920)
#define OFF_1 106496       // fc1_w  [5][2][128][64] swizzled   (81920)
#define WS_HALVES 188416

__global__ void convert_weights(const float* __restrict__ fc_p_w,
                                const float* __restrict__ fc_c_w,
                                const float* __restrict__ fc0_w,
                                const float* __restrict__ fc1_w,
                                _Float16* __restrict__ ws) {
  int i = blockIdx.x * 256 + threadIdx.x;
  if (i >= WS_HALVES) return;
  if (i < 4096) {  // Wp linear
    ws[OFF_P + i] = (_Float16)fc_p_w[i];
    return;
  }
  i -= 4096;
  if (i < 20480) {  // Wc linear
    ws[OFF_C + i] = (_Float16)fc_c_w[i];
    return;
  }
  i -= 20480;
  if (i < 81920) {  // W0: [5][2][64][128]; contiguous == fc0_w rows; swizzle cols
    const int row = i >> 7;  // global row index 0..639 (row&7 == local row&7)
    const int col = i & 127;
    const int gs = col >> 3, e = col & 7;
    ws[OFF_0 + i] = (_Float16)fc0_w[(row << 7) + (((gs ^ (row & 7)) << 3) | e)];
    return;
  }
  i -= 81920;
  {  // W1: [5][2 khalf][128 j][64 k] swizzled
    const int c4 = i >> 13;          // 0..9 = layer*2 + khalf
    const int li = c4 >> 1, h = c4 & 1;
    const int r = (i & 8191) >> 6;   // j 0..127
    const int cc = i & 63;
    const int gs = cc >> 3, e = cc & 7;
    const int k = (h << 6) + (((gs ^ (r & 7)) << 3) | e);
    ws[OFF_1 + i] = (_Float16)fc1_w[li * 16384 + (r << 7) + k];
  }
}

struct SMem {
  _Float16 NET[TQ * HD];   // 64KB, relu'd fp16, granule^(q&7); tail: f32 reduce
  _Float16 H[TQ * 64];     // 32KB, relu'd fp16 h-half; head: gather lat (80B rows)
  _Float16 WB[3][8192];    // 3 x 16KB weight chunk slots
};

__device__ __forceinline__ f16x4 relu_pack(const f32x4& a) {
  f16x4 r;
#pragma unroll
  for (int i = 0; i < 4; ++i) r[i] = (_Float16)fmaxf(a[i], 0.f);
  return r;
}

// fc0 half: h[q][0..63] = relu(NET) @ W0chunk^T + b, write relu'd to H
__device__ __forceinline__ void fc0_half(SMem& sm, int slot,
                                         const float* __restrict__ b0p, int qe,
                                         int lr, int lg) {
  f32x4 hacc[4][2];
#pragma unroll
  for (int jt = 0; jt < 4; ++jt) {
    const f32x4 bv = *(const f32x4*)(b0p + 16 * jt + 4 * lg);
    hacc[jt][0] = bv;
    hacc[jt][1] = bv;
  }
#pragma unroll
  for (int ks = 0; ks < 4; ++ks) {
    f16x8 af[4];
#pragma unroll
    for (int jt = 0; jt < 4; ++jt)
      af[jt] = *(const f16x8*)((const char*)sm.WB[slot] + (16 * jt + lr) * 256 +
                               (((4 * ks + lg) ^ (lr & 7)) << 4));
    f16x8 xf[2];
#pragma unroll
    for (int q2 = 0; q2 < 2; ++q2) {
      const int q = qe + 16 * q2 + lr;
      xf[q2] = *(const f16x8*)((const char*)sm.NET + q * 256 +
                               (((4 * ks + lg) ^ (q & 7)) << 4));
    }
#pragma unroll
    for (int jt = 0; jt < 4; ++jt)
#pragma unroll
      for (int q2 = 0; q2 < 2; ++q2)
        hacc[jt][q2] = __builtin_amdgcn_mfma_f32_16x16x32_f16(af[jt], xf[q2],
                                                              hacc[jt][q2], 0, 0, 0);
  }
#pragma unroll
  for (int jt = 0; jt < 4; ++jt)
#pragma unroll
    for (int q2 = 0; q2 < 2; ++q2) {
      const int q = qe + 16 * q2 + lr;
      const int G = (2 * jt + (lg >> 1)) ^ (q & 7);
      *(f16x4*)((char*)sm.H + q * 128 + (G << 4) + ((lg & 1) << 3)) =
          relu_pack(hacc[jt][q2]);
    }
}

// fc1 half: acc += H @ W1chunk^T  (k-partial)
__device__ __forceinline__ void fc1_half(SMem& sm, int slot, f32x4 (&acc)[4][4],
                                         int j0, int q0, int lr, int lg) {
#pragma unroll
  for (int ks = 0; ks < 2; ++ks) {
    f16x8 a1[4];
#pragma unroll
    for (int jt = 0; jt < 4; ++jt)
      a1[jt] = *(const f16x8*)((const char*)sm.WB[slot] + (j0 + 16 * jt + lr) * 128 +
                               (((4 * ks + lg) ^ (lr & 7)) << 4));
    f16x8 hf[4];
#pragma unroll
    for (int qt = 0; qt < 4; ++qt) {
      const int q = q0 + 16 * qt + lr;
      hf[qt] = *(const f16x8*)((const char*)sm.H + q * 128 +
                               (((4 * ks + lg) ^ (q & 7)) << 4));
    }
#pragma unroll
    for (int jt = 0; jt < 4; ++jt)
#pragma unroll
      for (int qt = 0; qt < 4; ++qt)
        acc[jt][qt] = __builtin_amdgcn_mfma_f32_16x16x32_f16(a1[jt], hf[qt],
                                                             acc[jt][qt], 0, 0, 0);
  }
}

__global__ __launch_bounds__(BLOCK, 2) void patch_decoder_kernel(
    const float* __restrict__ z_feats, const float* __restrict__ query,
    const _Float16* __restrict__ ws, const float* __restrict__ fc_p_b,
    const float* __restrict__ fc_c_b, const float* __restrict__ fc0_b,
    const float* __restrict__ fc1_b, const float* __restrict__ fc_out_w,
    const float* __restrict__ fc_out_b, float* __restrict__ out, int nq) {
  __shared__ SMem sm;
  const int t = threadIdx.x;
  const int w = t >> 6;
  const int l = t & 63;
  const int lr = l & 15, lg = l >> 4;
  const int j0 = (w & 1) << 6;     // main partition: j-half
  const int q0 = (w >> 1) << 6;    // main partition: q-quarter (64 q)
  const int qe = w << 5;           // fc0 phases: q-eighth (32 q)
  const int qbase = blockIdx.x * TQ;

  // ---- issue iter-0 weight-chunk loads (land during gather) ----
  uint4 st[8];
  {
    const char* w0b = (const char*)(ws + OFF_0);
    const char* w1b = (const char*)(ws + OFF_1);
    st[0] = *(const uint4*)(w0b + t * 16);            // C0 = W0 h0
    st[1] = *(const uint4*)(w0b + 8192 + t * 16);
    st[2] = *(const uint4*)(w1b + t * 16);            // C2 = W1 k0
    st[3] = *(const uint4*)(w1b + 8192 + t * 16);
    st[4] = *(const uint4*)(w0b + 16384 + t * 16);    // C1 = W0 h1
    st[5] = *(const uint4*)(w0b + 24576 + t * 16);
    st[6] = *(const uint4*)(w1b + 16384 + t * 16);    // C3 = W1 k1
    st[7] = *(const uint4*)(w1b + 24576 + t * 16);
  }

  // ---- gather: 2 threads/query, 16 feats each; lat -> H region (80B rows) ----
  {
    const int q = t >> 1, s = t & 1;
    const int qg = qbase + q;
    float acc[16];
#pragma unroll
    for (int e = 0; e < 16; ++e) acc[e] = 0.f;
    if (qg < nq) {
      const float qx = query[qg * 3 + 0];
      const float qy = query[qg * 3 + 1];
      const float qz = query[qg * 3 + 2];
      const float fx = floorf(qx), fy = floorf(qy), fz = floorf(qz);
      const float rx = qx - fx, ry = qy - fy, rz = qz - fz;
      const int bx = (int)fx, by = (int)fy, bz = (int)fz;
      const float wx[2] = {1.f - rx, rx}, wy[2] = {1.f - ry, ry},
                  wz[2] = {1.f - rz, rz};
#pragma unroll
      for (int c = 0; c < 8; ++c) {
        const int ox = (c >> 2) & 1, oy = (c >> 1) & 1, oz = c & 1;
        const float wgt = wx[ox] * wy[oy] * wz[oz];
        const float* f = z_feats +
                         (size_t)(((bx + ox) * GR + (by + oy)) * GR + (bz + oz)) * ZD +
                         s * 16;
#pragma unroll
        for (int v4 = 0; v4 < 4; ++v4) {
          const float4 v = *(const float4*)(f + v4 * 4);
          acc[v4 * 4 + 0] = fmaf(wgt, v.x, acc[v4 * 4 + 0]);
          acc[v4 * 4 + 1] = fmaf(wgt, v.y, acc[v4 * 4 + 1]);
          acc[v4 * 4 + 2] = fmaf(wgt, v.z, acc[v4 * 4 + 2]);
          acc[v4 * 4 + 3] = fmaf(wgt, v.w, acc[v4 * 4 + 3]);
        }
      }
    }
    f16x8 h0, h1;
#pragma unroll
    for (int e = 0; e < 8; ++e) {
      h0[e] = (_Float16)acc[e];
      h1[e] = (_Float16)acc[8 + e];
    }
    char* lb = (char*)sm.H + q * 80 + s * 32;
    *(f16x8*)lb = h0;
    *(f16x8*)(lb + 16) = h1;
  }

  // stage iter-0 chunks into slots 0,1,2 (C0,C2,C1)
  {
    char* s0 = (char*)sm.WB[0];
    *(uint4*)(s0 + t * 16) = st[0];
    *(uint4*)(s0 + 8192 + t * 16) = st[1];
    char* s1 = (char*)sm.WB[1];
    *(uint4*)(s1 + t * 16) = st[2];
    *(uint4*)(s1 + 8192 + t * 16) = st[3];
    char* s2 = (char*)sm.WB[2];
    *(uint4*)(s2 + t * 16) = st[4];
    *(uint4*)(s2 + 8192 + t * 16) = st[5];
  }
  __syncthreads();  // bar0: lat + slots visible

  // ---- latf (persist) + fc_p ----
  f16x8 latf[4];
#pragma unroll
  for (int qt = 0; qt < 4; ++qt)
    latf[qt] = *(const f16x8*)((const char*)sm.H + (q0 + 16 * qt + lr) * 80 + lg * 16);

  f32x4 acc[4][4];
#pragma unroll
  for (int jt = 0; jt < 4; ++jt) {
    const f32x4 bv = *(const f32x4*)(fc_p_b + j0 + 16 * jt + 4 * lg);
#pragma unroll
    for (int qt = 0; qt < 4; ++qt) acc[jt][qt] = bv;
  }
#pragma unroll
  for (int jt = 0; jt < 4; ++jt) {
    const f16x8 wf = *(const f16x8*)(ws + OFF_P + (j0 + 16 * jt + lr) * 32 + lg * 8);
#pragma unroll
    for (int qt = 0; qt < 4; ++qt)
      acc[jt][qt] = __builtin_amdgcn_mfma_f32_16x16x32_f16(wf, latf[qt], acc[jt][qt],
                                                           0, 0, 0);
  }

#pragma unroll 1
  for (int i = 0; i < NBLK; ++i) {
    // ---- P0: fc_c (direct-global frags) + bias ----
#pragma unroll
    for (int jt = 0; jt < 4; ++jt) {
      const f16x8 wf =
          *(const f16x8*)(ws + OFF_C + i * 4096 + (j0 + 16 * jt + lr) * 32 + lg * 8);
#pragma unroll
      for (int qt = 0; qt < 4; ++qt)
        acc[jt][qt] = __builtin_amdgcn_mfma_f32_16x16x32_f16(wf, latf[qt],
                                                             acc[jt][qt], 0, 0, 0);
      const f32x4 bv = *(const f32x4*)(fc_c_b + i * HD + j0 + 16 * jt + 4 * lg);
#pragma unroll
      for (int qt = 0; qt < 4; ++qt) acc[jt][qt] += bv;
    }
    // write relu(net) -> NET (fp16, swizzled)
#pragma unroll
    for (int jt = 0; jt < 4; ++jt)
#pragma unroll
      for (int qt = 0; qt < 4; ++qt) {
        const int q = q0 + 16 * qt + lr;
        const int G = ((j0 >> 3) + 2 * jt + (lg >> 1)) ^ (q & 7);
        *(f16x4*)((char*)sm.NET + q * 256 + (G << 4) + ((lg & 1) << 3)) =
            relu_pack(acc[jt][qt]);
      }
    // stage this iter's chunks (loaded during prev iter's P2) for i>0
    if (i > 0) {
      char* s0 = (char*)sm.WB[0];
      *(uint4*)(s0 + t * 16) = st[0];
      *(uint4*)(s0 + 8192 + t * 16) = st[1];
      char* s1 = (char*)sm.WB[1];
      *(uint4*)(s1 + t * 16) = st[2];
      *(uint4*)(s1 + 8192 + t * 16) = st[3];
      char* s2 = (char*)sm.WB[2];
      *(uint4*)(s2 + t * 16) = st[4];
      *(uint4*)(s2 + 8192 + t * 16) = st[5];
    }
    __syncthreads();  // bar1: NET + slots ready; prev H reads done

    // ---- P1: h0 = relu(NET) @ W0h0 ----
    fc0_half(sm, 0, fc0_b + i * HD, qe, lr, lg);
    __syncthreads();  // bar2: H(k0) ready; slot0 reads done

    // C3 -> slot0; issue next iter's loads
    {
      char* s0 = (char*)sm.WB[0];
      *(uint4*)(s0 + t * 16) = st[6];
      *(uint4*)(s0 + 8192 + t * 16) = st[7];
    }
    if (i + 1 < NBLK) {
      const char* w0b = (const char*)(ws + OFF_0) + (size_t)(i + 1) * 32768;
      const char* w1b = (const char*)(ws + OFF_1) + (size_t)(i + 1) * 32768;
      st[0] = *(const uint4*)(w0b + t * 16);
      st[1] = *(const uint4*)(w0b + 8192 + t * 16);
      st[2] = *(const uint4*)(w1b + t * 16);
      st[3] = *(const uint4*)(w1b + 8192 + t * 16);
      st[4] = *(const uint4*)(w0b + 16384 + t * 16);
      st[5] = *(const uint4*)(w0b + 24576 + t * 16);
      st[6] = *(const uint4*)(w1b + 16384 + t * 16);
      st[7] = *(const uint4*)(w1b + 24576 + t * 16);
    }

    // ---- P2: dx += H @ W1k0 ----
    fc1_half(sm, 1, acc, j0, q0, lr, lg);
    __syncthreads();  // bar3: H(k0) reads done

    // ---- P3: h1 = relu(NET) @ W0h1 ----
    fc0_half(sm, 2, fc0_b + i * HD + 64, qe, lr, lg);
    __syncthreads();  // bar4: H(k1) ready; C3 write visible

    // ---- P4: dx += H @ W1k1 ; net += b1 ----
    fc1_half(sm, 0, acc, j0, q0, lr, lg);
#pragma unroll
    for (int jt = 0; jt < 4; ++jt) {
      const f32x4 bv = *(const f32x4*)(fc1_b + i * HD + j0 + 16 * jt + 4 * lg);
#pragma unroll
      for (int qt = 0; qt < 4; ++qt) acc[jt][qt] += bv;
    }
  }

  // ---- epilogue: out[q] = leaky(net) . wout + b ----
  float* red = (float*)sm.NET;  // [2][256] f32 partials (NET dead)
  {
    float p[4];
#pragma unroll
    for (int qt = 0; qt < 4; ++qt) p[qt] = 0.f;
#pragma unroll
    for (int jt = 0; jt < 4; ++jt) {
      const f32x4 wv = *(const f32x4*)(fc_out_w + j0 + 16 * jt + 4 * lg);
#pragma unroll
      for (int qt = 0; qt < 4; ++qt) {
        const f32x4 a = acc[jt][qt];
#pragma unroll
        for (int r = 0; r < 4; ++r) {
          const float v = (a[r] > 0.f) ? a[r] : 0.2f * a[r];
          p[qt] = fmaf(v, wv[r], p[qt]);
        }
      }
    }
#pragma unroll
    for (int qt = 0; qt < 4; ++qt) {
      p[qt] += __shfl_xor(p[qt], 16);
      p[qt] += __shfl_xor(p[qt], 32);
    }
    __syncthreads();  // ensure all NET reads (none remain) / reuse safe
    if (lg == 0) {
#pragma unroll
      for (int qt = 0; qt < 4; ++qt) red[(w & 1) * 256 + q0 + 16 * qt + lr] = p[qt];
    }
  }
  __syncthreads();
  if (t < TQ) {
    const int qg = qbase + t;
    if (qg < nq) out[qg] = red[t] + red[256 + t] + fc_out_b[0];
  }
}

extern "C" void kernel_launch(void* const* d_in, const int* in_sizes, int n_in,
                              void* d_out, int out_size, void* d_ws,
                              size_t ws_size, hipStream_t stream) {
  const float* z_feats = (const float*)d_in[0];
  const float* query = (const float*)d_in[1];
  const float* fc_p_w = (const float*)d_in[2];
  const float* fc_p_b = (const float*)d_in[3];
  const float* fc_c_w = (const float*)d_in[4];
  const float* fc_c_b = (const float*)d_in[5];
  const float* fc0_w = (const float*)d_in[6];
  const float* fc0_b = (const float*)d_in[7];
  const float* fc1_w = (const float*)d_in[8];
  const float* fc1_b = (const float*)d_in[9];
  const float* fc_out_w = (const float*)d_in[10];
  const float* fc_out_b = (const float*)d_in[11];
  float* out = (float*)d_out;
  _Float16* ws = (_Float16*)d_ws;

  const int nq = in_sizes[1] / 3;

  convert_weights<<<(WS_HALVES + 255) / 256, 256, 0, stream>>>(fc_p_w, fc_c_w,
                                                               fc0_w, fc1_w, ws);
  const int grid = (nq + TQ - 1) / TQ;
  patch_decoder_kernel<<<grid, BLOCK, 0, stream>>>(z_feats, query, ws, fc_p_b,
                                                   fc_c_b, fc0_b, fc1_b, fc_out_w,
                                                   fc_out_b, out, nq);
}

// Round 4
// 330.389 us; speedup vs baseline: 20.3254x; 1.3944x over previous
//
#include <hip/hip_runtime.h>

// PatchDecoder round 4: fp16 MFMA, TQ=256, async weight staging via
// global_load_lds (NO staging registers -> no spills; R3's 348MB scratch
// writeback eliminated), race-free rotating slot schedule.
//
// d_ws (fp16): Wp [128][32], Wc [5][128][32] (frags read DIRECT from global),
//   W0 [5][2 jhalf][64][128] swizzled 16KB chunks,
//   W1 [5][2 khalf][128][64] swizzled 16KB chunks.
//
// Main kernel: 512 thr = 8 waves, TQ=256.
//   Main partition: wave w -> j-half (w&1), q-quarter (w>>1); acc[4jt][4qt] f32x4
//   f32 register-resident across all layers.
//   fc0 phases partition by q-eighth (w*32), all 64 j of current half.
//   Slots (16KB each): aslot=i&1 holds W0h0(i), bslot=1-aslot holds W1k0(i),
//   slot2 holds W0h1(i); W1k1(i) -> aslot after its P1 readers retire.
//   Every global_load_lds is issued immediately after the barrier that retires
//   the slot's readers and >=1 barrier before its consumer (compiler drains
//   vmcnt(0) at each __syncthreads -> latency hidden, correctness guaranteed).
// LDS: NET 64KB + H 32KB (aliases gather lat + epilogue reduce) + 3x16KB = 144KB.

#define TQ 256
#define BLOCK 512
#define HD 128
#define ZD 32
#define NBLK 5
#define GR 64

typedef _Float16 f16x8 __attribute__((ext_vector_type(8)));
typedef _Float16 f16x4 __attribute__((ext_vector_type(4)));
typedef float f32x4 __attribute__((ext_vector_type(4)));

// d_ws layout in halves
#define OFF_P 0            // fc_p_w [128][32]                  (4096)
#define OFF_C 4096         // fc_c_w [5][128][32]               (20480)
#define OFF_0 24576        // fc0_w  [5][2][64][128] swizzled   (81920)
#define OFF_1 106496       // fc1_w  [5][2][128][64] swizzled   (81920)
#define WS_HALVES 188416

__global__ void convert_weights(const float* __restrict__ fc_p_w,
                                const float* __restrict__ fc_c_w,
                                const float* __restrict__ fc0_w,
                                const float* __restrict__ fc1_w,
                                _Float16* __restrict__ ws) {
  int i = blockIdx.x * 256 + threadIdx.x;
  if (i >= WS_HALVES) return;
  if (i < 4096) {  // Wp linear
    ws[OFF_P + i] = (_Float16)fc_p_w[i];
    return;
  }
  i -= 4096;
  if (i < 20480) {  // Wc linear
    ws[OFF_C + i] = (_Float16)fc_c_w[i];
    return;
  }
  i -= 20480;
  if (i < 81920) {  // W0: [5][2][64][128]; rows contiguous; swizzle cols
    const int row = i >> 7;
    const int col = i & 127;
    const int gs = col >> 3, e = col & 7;
    ws[OFF_0 + i] = (_Float16)fc0_w[(row << 7) + (((gs ^ (row & 7)) << 3) | e)];
    return;
  }
  i -= 81920;
  {  // W1: [5][2 khalf][128 j][64 k] swizzled
    const int c4 = i >> 13;          // layer*2 + khalf
    const int li = c4 >> 1, h = c4 & 1;
    const int r = (i & 8191) >> 6;   // j 0..127
    const int cc = i & 63;
    const int gs = cc >> 3, e = cc & 7;
    const int k = (h << 6) + (((gs ^ (r & 7)) << 3) | e);
    ws[OFF_1 + i] = (_Float16)fc1_w[li * 16384 + (r << 7) + k];
  }
}

struct SMem {
  _Float16 NET[TQ * HD];   // 64KB, relu'd fp16, granule^(q&7); tail: f32 reduce
  _Float16 H[TQ * 64];     // 32KB, relu'd fp16 h-half; head: gather lat (80B rows)
  _Float16 WB[3][8192];    // 3 x 16KB weight chunk slots
};

// async stage one 16KB chunk: 512 threads x 16B x 2 issues, LDS-linear
__device__ __forceinline__ void stage_chunk(char* lds, const char* g, int t) {
  __builtin_amdgcn_global_load_lds(
      (const __attribute__((address_space(1))) void*)(g + t * 16),
      (__attribute__((address_space(3))) void*)(lds + t * 16), 16, 0, 0);
  __builtin_amdgcn_global_load_lds(
      (const __attribute__((address_space(1))) void*)(g + 8192 + t * 16),
      (__attribute__((address_space(3))) void*)(lds + 8192 + t * 16), 16, 0, 0);
}

__device__ __forceinline__ f16x4 relu_pack(const f32x4& a) {
  f16x4 r;
#pragma unroll
  for (int i = 0; i < 4; ++i) r[i] = (_Float16)fmaxf(a[i], 0.f);
  return r;
}

// fc0 half: h[q][0..63] = relu(NET) @ W0chunk^T + b, write relu'd to H
__device__ __forceinline__ void fc0_half(SMem& sm, int slot,
                                         const float* __restrict__ b0p, int qe,
                                         int lr, int lg) {
  f32x4 hacc[4][2];
#pragma unroll
  for (int jt = 0; jt < 4; ++jt) {
    const f32x4 bv = *(const f32x4*)(b0p + 16 * jt + 4 * lg);
    hacc[jt][0] = bv;
    hacc[jt][1] = bv;
  }
#pragma unroll
  for (int ks = 0; ks < 4; ++ks) {
    f16x8 af[4];
#pragma unroll
    for (int jt = 0; jt < 4; ++jt)
      af[jt] = *(const f16x8*)((const char*)sm.WB[slot] + (16 * jt + lr) * 256 +
                               (((4 * ks + lg) ^ (lr & 7)) << 4));
    f16x8 xf[2];
#pragma unroll
    for (int q2 = 0; q2 < 2; ++q2) {
      const int q = qe + 16 * q2 + lr;
      xf[q2] = *(const f16x8*)((const char*)sm.NET + q * 256 +
                               (((4 * ks + lg) ^ (q & 7)) << 4));
    }
#pragma unroll
    for (int jt = 0; jt < 4; ++jt)
#pragma unroll
      for (int q2 = 0; q2 < 2; ++q2)
        hacc[jt][q2] = __builtin_amdgcn_mfma_f32_16x16x32_f16(af[jt], xf[q2],
                                                              hacc[jt][q2], 0, 0, 0);
  }
#pragma unroll
  for (int jt = 0; jt < 4; ++jt)
#pragma unroll
    for (int q2 = 0; q2 < 2; ++q2) {
      const int q = qe + 16 * q2 + lr;
      const int G = (2 * jt + (lg >> 1)) ^ (q & 7);
      *(f16x4*)((char*)sm.H + q * 128 + (G << 4) + ((lg & 1) << 3)) =
          relu_pack(hacc[jt][q2]);
    }
}

// fc1 half: acc += H @ W1chunk^T  (k-partial)
__device__ __forceinline__ void fc1_half(SMem& sm, int slot, f32x4 (&acc)[4][4],
                                         int j0, int q0, int lr, int lg) {
#pragma unroll
  for (int ks = 0; ks < 2; ++ks) {
    f16x8 a1[4];
#pragma unroll
    for (int jt = 0; jt < 4; ++jt)
      a1[jt] = *(const f16x8*)((const char*)sm.WB[slot] + (j0 + 16 * jt + lr) * 128 +
                               (((4 * ks + lg) ^ (lr & 7)) << 4));
    f16x8 hf[4];
#pragma unroll
    for (int qt = 0; qt < 4; ++qt) {
      const int q = q0 + 16 * qt + lr;
      hf[qt] = *(const f16x8*)((const char*)sm.H + q * 128 +
                               (((4 * ks + lg) ^ (q & 7)) << 4));
    }
#pragma unroll
    for (int jt = 0; jt < 4; ++jt)
#pragma unroll
      for (int qt = 0; qt < 4; ++qt)
        acc[jt][qt] = __builtin_amdgcn_mfma_f32_16x16x32_f16(a1[jt], hf[qt],
                                                             acc[jt][qt], 0, 0, 0);
  }
}

__global__ __launch_bounds__(BLOCK, 2) void patch_decoder_kernel(
    const float* __restrict__ z_feats, const float* __restrict__ query,
    const _Float16* __restrict__ ws, const float* __restrict__ fc_p_b,
    const float* __restrict__ fc_c_b, const float* __restrict__ fc0_b,
    const float* __restrict__ fc1_b, const float* __restrict__ fc_out_w,
    const float* __restrict__ fc_out_b, float* __restrict__ out, int nq) {
  __shared__ SMem sm;
  const int t = threadIdx.x;
  const int w = t >> 6;
  const int l = t & 63;
  const int lr = l & 15, lg = l >> 4;
  const int j0 = (w & 1) << 6;     // main partition: j-half
  const int q0 = (w >> 1) << 6;    // main partition: q-quarter (64 q)
  const int qe = w << 5;           // fc0 phases: q-eighth (32 q)
  const int qbase = blockIdx.x * TQ;

  const char* w0base = (const char*)(ws + OFF_0);
  const char* w1base = (const char*)(ws + OFF_1);

  // ---- prologue: async-stage iter-0 chunks (land during gather) ----
  stage_chunk((char*)sm.WB[0], w0base, t);          // W0h0(0) -> aslot(0)=0
  stage_chunk((char*)sm.WB[1], w1base, t);          // W1k0(0) -> bslot(0)=1
  stage_chunk((char*)sm.WB[2], w0base + 16384, t);  // W0h1(0) -> s2

  // ---- gather: 2 threads/query, 16 feats each; lat -> H region (80B rows) ----
  {
    const int q = t >> 1, s = t & 1;
    const int qg = qbase + q;
    float acc[16];
#pragma unroll
    for (int e = 0; e < 16; ++e) acc[e] = 0.f;
    if (qg < nq) {
      const float qx = query[qg * 3 + 0];
      const float qy = query[qg * 3 + 1];
      const float qz = query[qg * 3 + 2];
      const float fx = floorf(qx), fy = floorf(qy), fz = floorf(qz);
      const float rx = qx - fx, ry = qy - fy, rz = qz - fz;
      const int bx = (int)fx, by = (int)fy, bz = (int)fz;
      const float wx[2] = {1.f - rx, rx}, wy[2] = {1.f - ry, ry},
                  wz[2] = {1.f - rz, rz};
#pragma unroll
      for (int c = 0; c < 8; ++c) {
        const int ox = (c >> 2) & 1, oy = (c >> 1) & 1, oz = c & 1;
        const float wgt = wx[ox] * wy[oy] * wz[oz];
        const float* f = z_feats +
                         (size_t)(((bx + ox) * GR + (by + oy)) * GR + (bz + oz)) * ZD +
                         s * 16;
#pragma unroll
        for (int v4 = 0; v4 < 4; ++v4) {
          const float4 v = *(const float4*)(f + v4 * 4);
          acc[v4 * 4 + 0] = fmaf(wgt, v.x, acc[v4 * 4 + 0]);
          acc[v4 * 4 + 1] = fmaf(wgt, v.y, acc[v4 * 4 + 1]);
          acc[v4 * 4 + 2] = fmaf(wgt, v.z, acc[v4 * 4 + 2]);
          acc[v4 * 4 + 3] = fmaf(wgt, v.w, acc[v4 * 4 + 3]);
        }
      }
    }
    f16x8 h0, h1;
#pragma unroll
    for (int e = 0; e < 8; ++e) {
      h0[e] = (_Float16)acc[e];
      h1[e] = (_Float16)acc[8 + e];
    }
    char* lb = (char*)sm.H + q * 80 + s * 32;
    *(f16x8*)lb = h0;
    *(f16x8*)(lb + 16) = h1;
  }
  __syncthreads();  // bar0: lat visible; prologue chunks drained

  // ---- latf (persist) + fc_p ----
  f16x8 latf[4];
#pragma unroll
  for (int qt = 0; qt < 4; ++qt)
    latf[qt] = *(const f16x8*)((const char*)sm.H + (q0 + 16 * qt + lr) * 80 + lg * 16);

  f32x4 acc[4][4];
#pragma unroll
  for (int jt = 0; jt < 4; ++jt) {
    const f32x4 bv = *(const f32x4*)(fc_p_b + j0 + 16 * jt + 4 * lg);
#pragma unroll
    for (int qt = 0; qt < 4; ++qt) acc[jt][qt] = bv;
  }
#pragma unroll
  for (int jt = 0; jt < 4; ++jt) {
    const f16x8 wf = *(const f16x8*)(ws + OFF_P + (j0 + 16 * jt + lr) * 32 + lg * 8);
#pragma unroll
    for (int qt = 0; qt < 4; ++qt)
      acc[jt][qt] = __builtin_amdgcn_mfma_f32_16x16x32_f16(wf, latf[qt], acc[jt][qt],
                                                           0, 0, 0);
  }

#pragma unroll 1
  for (int i = 0; i < NBLK; ++i) {
    const int as = i & 1, bs = as ^ 1;
    // ---- P0: fc_c (direct-global frags) + bias; write relu(net) -> NET ----
#pragma unroll
    for (int jt = 0; jt < 4; ++jt) {
      const f16x8 wf =
          *(const f16x8*)(ws + OFF_C + i * 4096 + (j0 + 16 * jt + lr) * 32 + lg * 8);
#pragma unroll
      for (int qt = 0; qt < 4; ++qt)
        acc[jt][qt] = __builtin_amdgcn_mfma_f32_16x16x32_f16(wf, latf[qt],
                                                             acc[jt][qt], 0, 0, 0);
      const f32x4 bv = *(const f32x4*)(fc_c_b + i * HD + j0 + 16 * jt + 4 * lg);
#pragma unroll
      for (int qt = 0; qt < 4; ++qt) acc[jt][qt] += bv;
    }
#pragma unroll
    for (int jt = 0; jt < 4; ++jt)
#pragma unroll
      for (int qt = 0; qt < 4; ++qt) {
        const int q = q0 + 16 * qt + lr;
        const int G = ((j0 >> 3) + 2 * jt + (lg >> 1)) ^ (q & 7);
        *(f16x4*)((char*)sm.NET + q * 256 + (G << 4) + ((lg & 1) << 3)) =
            relu_pack(acc[jt][qt]);
      }
    __syncthreads();  // bar1: NET ready; prev-iter P4 readers of slot[bs] done

    if (i > 0) stage_chunk((char*)sm.WB[bs], w1base + i * 32768, t);  // W1k0(i)
    // ---- P1: h0 = relu(NET) @ W0h0 ----
    fc0_half(sm, as, fc0_b + i * HD, qe, lr, lg);
    __syncthreads();  // bar2: H(k0) ready; slot[as] readers done

    stage_chunk((char*)sm.WB[as], w1base + i * 32768 + 16384, t);  // W1k1(i)
    // ---- P2: dx += H @ W1k0 ----
    fc1_half(sm, bs, acc, j0, q0, lr, lg);
    __syncthreads();  // bar3: H(k0) reads done; slot[bs] readers done

    if (i + 1 < NBLK)
      stage_chunk((char*)sm.WB[bs], w0base + (i + 1) * 32768, t);  // W0h0(i+1)
    // ---- P3: h1 = relu(NET) @ W0h1 ----
    fc0_half(sm, 2, fc0_b + i * HD + 64, qe, lr, lg);
    __syncthreads();  // bar4: H(k1) ready; slot2 readers done; W1k1 drained

    if (i + 1 < NBLK)
      stage_chunk((char*)sm.WB[2], w0base + (i + 1) * 32768 + 16384, t);  // W0h1(i+1)
    // ---- P4: dx += H @ W1k1 ; net += b1 ----
    fc1_half(sm, as, acc, j0, q0, lr, lg);
#pragma unroll
    for (int jt = 0; jt < 4; ++jt) {
      const f32x4 bv = *(const f32x4*)(fc1_b + i * HD + j0 + 16 * jt + 4 * lg);
#pragma unroll
      for (int qt = 0; qt < 4; ++qt) acc[jt][qt] += bv;
    }
  }

  // ---- epilogue: out[q] = leaky(net) . wout + b ----
  float* red = (float*)sm.NET;  // [2][256] f32 partials (NET dead)
  {
    float p[4];
#pragma unroll
    for (int qt = 0; qt < 4; ++qt) p[qt] = 0.f;
#pragma unroll
    for (int jt = 0; jt < 4; ++jt) {
      const f32x4 wv = *(const f32x4*)(fc_out_w + j0 + 16 * jt + 4 * lg);
#pragma unroll
      for (int qt = 0; qt < 4; ++qt) {
        const f32x4 a = acc[jt][qt];
#pragma unroll
        for (int r = 0; r < 4; ++r) {
          const float v = (a[r] > 0.f) ? a[r] : 0.2f * a[r];
          p[qt] = fmaf(v, wv[r], p[qt]);
        }
      }
    }
#pragma unroll
    for (int qt = 0; qt < 4; ++qt) {
      p[qt] += __shfl_xor(p[qt], 16);
      p[qt] += __shfl_xor(p[qt], 32);
    }
    __syncthreads();  // last NET readers (P3) retired at bar4; safe to reuse
    if (lg == 0) {
#pragma unroll
      for (int qt = 0; qt < 4; ++qt) red[(w & 1) * 256 + q0 + 16 * qt + lr] = p[qt];
    }
  }
  __syncthreads();
  if (t < TQ) {
    const int qg = qbase + t;
    if (qg < nq) out[qg] = red[t] + red[256 + t] + fc_out_b[0];
  }
}

extern "C" void kernel_launch(void* const* d_in, const int* in_sizes, int n_in,
                              void* d_out, int out_size, void* d_ws,
                              size_t ws_size, hipStream_t stream) {
  const float* z_feats = (const float*)d_in[0];
  const float* query = (const float*)d_in[1];
  const float* fc_p_w = (const float*)d_in[2];
  const float* fc_p_b = (const float*)d_in[3];
  const float* fc_c_w = (const float*)d_in[4];
  const float* fc_c_b = (const float*)d_in[5];
  const float* fc0_w = (const float*)d_in[6];
  const float* fc0_b = (const float*)d_in[7];
  const float* fc1_w = (const float*)d_in[8];
  const float* fc1_b = (const float*)d_in[9];
  const float* fc_out_w = (const float*)d_in[10];
  const float* fc_out_b = (const float*)d_in[11];
  float* out = (float*)d_out;
  _Float16* ws = (_Float16*)d_ws;

  const int nq = in_sizes[1] / 3;

  convert_weights<<<(WS_HALVES + 255) / 256, 256, 0, stream>>>(fc_p_w, fc_c_w,
                                                               fc0_w, fc1_w, ws);
  const int grid = (nq + TQ - 1) / TQ;
  patch_decoder_kernel<<<grid, BLOCK, 0, stream>>>(z_feats, query, ws, fc_p_b,
                                                   fc_c_b, fc0_b, fc1_b, fc_out_w,
                                                   fc_out_b, out, nq);
}

// Round 5
// 277.679 us; speedup vs baseline: 24.1836x; 1.1898x over previous
//
#include <hip/hip_runtime.h>

// PatchDecoder round 5: fp16 MFMA, TQ=128 / BLOCK=256 / 2 weight slots ->
// LDS exactly 80KB -> 2 blocks/CU. Two independent blocks at decorrelated
// phases fill each other's barrier/latency stalls (R4 was 1 block/CU).
//
// d_ws (fp16): Wp [128][32], Wc [5][128][32] (frags read DIRECT from global),
//   W0 [5][2 jhalf][64][128] swizzled 16KB chunks,
//   W1 [5][2 khalf][128][64] swizzled 16KB chunks.
//
// Main kernel: 256 thr = 4 waves, TQ=128.
//   Main partition (fc_p/fc_c/fc1/epilogue): wave w -> j-half (w&1),
//   q-half (w>>1, 64q); acc[4jt][4qt] f32x4 register-resident.
//   fc0 phases: wave w -> q-quarter (32q, qe=w*32), full 64j of chunk.
//   Slots A/B (16KB): A carries W0h0->W0h1->W0h0(i+1), B carries
//   W1k0->W1k1->W1k0(i+1). Each global_load_lds issued right after the
//   barrier that retires the slot's readers, >=1 full phase before use.
//   4 barriers/iter (P4 -> next P0 needs none: P0 writes NET whose last
//   readers retired at bar4).
// LDS: NET 32KB + H 16KB (aliases gather-lat + epilogue reduce) + 2x16KB
//      = 81920 B exactly; 2 blocks = 163840 B = full 160 KiB CU capacity.

#define TQ 128
#define BLOCK 256
#define HD 128
#define ZD 32
#define NBLK 5
#define GR 64

typedef _Float16 f16x8 __attribute__((ext_vector_type(8)));
typedef _Float16 f16x4 __attribute__((ext_vector_type(4)));
typedef float f32x4 __attribute__((ext_vector_type(4)));

// d_ws layout in halves
#define OFF_P 0            // fc_p_w [128][32]                  (4096)
#define OFF_C 4096         // fc_c_w [5][128][32]               (20480)
#define OFF_0 24576        // fc0_w  [5][2][64][128] swizzled   (81920)
#define OFF_1 106496       // fc1_w  [5][2][128][64] swizzled   (81920)
#define WS_HALVES 188416

__global__ void convert_weights(const float* __restrict__ fc_p_w,
                                const float* __restrict__ fc_c_w,
                                const float* __restrict__ fc0_w,
                                const float* __restrict__ fc1_w,
                                _Float16* __restrict__ ws) {
  int i = blockIdx.x * 256 + threadIdx.x;
  if (i >= WS_HALVES) return;
  if (i < 4096) {  // Wp linear
    ws[OFF_P + i] = (_Float16)fc_p_w[i];
    return;
  }
  i -= 4096;
  if (i < 20480) {  // Wc linear
    ws[OFF_C + i] = (_Float16)fc_c_w[i];
    return;
  }
  i -= 20480;
  if (i < 81920) {  // W0: [5][2][64][128]; rows contiguous; swizzle cols
    const int row = i >> 7;
    const int col = i & 127;
    const int gs = col >> 3, e = col & 7;
    ws[OFF_0 + i] = (_Float16)fc0_w[(row << 7) + (((gs ^ (row & 7)) << 3) | e)];
    return;
  }
  i -= 81920;
  {  // W1: [5][2 khalf][128 j][64 k] swizzled
    const int c4 = i >> 13;          // layer*2 + khalf
    const int li = c4 >> 1, h = c4 & 1;
    const int r = (i & 8191) >> 6;   // j 0..127
    const int cc = i & 63;
    const int gs = cc >> 3, e = cc & 7;
    const int k = (h << 6) + (((gs ^ (r & 7)) << 3) | e);
    ws[OFF_1 + i] = (_Float16)fc1_w[li * 16384 + (r << 7) + k];
  }
}

struct SMem {
  _Float16 NET[TQ * HD];   // 32KB, relu'd fp16, granule^(q&7); head: gather lat
  _Float16 H[TQ * 64];     // 16KB, relu'd fp16 h-half; tail: epilogue reduce
  _Float16 WB[2][8192];    // 2 x 16KB weight chunk slots
};

// async stage one 16KB chunk: 256 threads x 16B x 4 issues, LDS-linear
__device__ __forceinline__ void stage_chunk(char* lds, const char* g, int t) {
#pragma unroll
  for (int r = 0; r < 4; ++r) {
    __builtin_amdgcn_global_load_lds(
        (const __attribute__((address_space(1))) void*)(g + r * 4096 + t * 16),
        (__attribute__((address_space(3))) void*)(lds + r * 4096 + t * 16), 16,
        0, 0);
  }
}

__device__ __forceinline__ f16x4 relu_pack(const f32x4& a) {
  f16x4 r;
#pragma unroll
  for (int i = 0; i < 4; ++i) r[i] = (_Float16)fmaxf(a[i], 0.f);
  return r;
}

// fc0 half: h[q][0..63] = relu(NET) @ W0chunk^T + b, write relu'd to H
__device__ __forceinline__ void fc0_half(SMem& sm, int slot,
                                         const float* __restrict__ b0p, int qe,
                                         int lr, int lg) {
  f32x4 hacc[4][2];
#pragma unroll
  for (int jt = 0; jt < 4; ++jt) {
    const f32x4 bv = *(const f32x4*)(b0p + 16 * jt + 4 * lg);
    hacc[jt][0] = bv;
    hacc[jt][1] = bv;
  }
#pragma unroll
  for (int ks = 0; ks < 4; ++ks) {
    f16x8 af[4];
#pragma unroll
    for (int jt = 0; jt < 4; ++jt)
      af[jt] = *(const f16x8*)((const char*)sm.WB[slot] + (16 * jt + lr) * 256 +
                               (((4 * ks + lg) ^ (lr & 7)) << 4));
    f16x8 xf[2];
#pragma unroll
    for (int q2 = 0; q2 < 2; ++q2) {
      const int q = qe + 16 * q2 + lr;
      xf[q2] = *(const f16x8*)((const char*)sm.NET + q * 256 +
                               (((4 * ks + lg) ^ (q & 7)) << 4));
    }
#pragma unroll
    for (int jt = 0; jt < 4; ++jt)
#pragma unroll
      for (int q2 = 0; q2 < 2; ++q2)
        hacc[jt][q2] = __builtin_amdgcn_mfma_f32_16x16x32_f16(af[jt], xf[q2],
                                                              hacc[jt][q2], 0, 0, 0);
  }
#pragma unroll
  for (int jt = 0; jt < 4; ++jt)
#pragma unroll
    for (int q2 = 0; q2 < 2; ++q2) {
      const int q = qe + 16 * q2 + lr;
      const int G = (2 * jt + (lg >> 1)) ^ (q & 7);
      *(f16x4*)((char*)sm.H + q * 128 + (G << 4) + ((lg & 1) << 3)) =
          relu_pack(hacc[jt][q2]);
    }
}

// fc1 half: acc += H @ W1chunk^T  (k-partial)
__device__ __forceinline__ void fc1_half(SMem& sm, int slot, f32x4 (&acc)[4][4],
                                         int j0, int q0, int lr, int lg) {
#pragma unroll
  for (int ks = 0; ks < 2; ++ks) {
    f16x8 a1[4];
#pragma unroll
    for (int jt = 0; jt < 4; ++jt)
      a1[jt] = *(const f16x8*)((const char*)sm.WB[slot] + (j0 + 16 * jt + lr) * 128 +
                               (((4 * ks + lg) ^ (lr & 7)) << 4));
    f16x8 hf[4];
#pragma unroll
    for (int qt = 0; qt < 4; ++qt) {
      const int q = q0 + 16 * qt + lr;
      hf[qt] = *(const f16x8*)((const char*)sm.H + q * 128 +
                               (((4 * ks + lg) ^ (q & 7)) << 4));
    }
#pragma unroll
    for (int jt = 0; jt < 4; ++jt)
#pragma unroll
      for (int qt = 0; qt < 4; ++qt)
        acc[jt][qt] = __builtin_amdgcn_mfma_f32_16x16x32_f16(a1[jt], hf[qt],
                                                             acc[jt][qt], 0, 0, 0);
  }
}

__global__ __launch_bounds__(BLOCK, 2) void patch_decoder_kernel(
    const float* __restrict__ z_feats, const float* __restrict__ query,
    const _Float16* __restrict__ ws, const float* __restrict__ fc_p_b,
    const float* __restrict__ fc_c_b, const float* __restrict__ fc0_b,
    const float* __restrict__ fc1_b, const float* __restrict__ fc_out_w,
    const float* __restrict__ fc_out_b, float* __restrict__ out, int nq) {
  __shared__ SMem sm;
  const int t = threadIdx.x;
  const int w = t >> 6;
  const int l = t & 63;
  const int lr = l & 15, lg = l >> 4;
  const int j0 = (w & 1) << 6;     // main partition: j-half
  const int q0 = (w >> 1) << 6;    // main partition: q-half (64 q)
  const int qe = w << 5;           // fc0 phases: q-quarter (32 q)
  const int qbase = blockIdx.x * TQ;

  const char* w0base = (const char*)(ws + OFF_0);
  const char* w1base = (const char*)(ws + OFF_1);

  // ---- prologue: async-stage iter-0 chunks (land during gather) ----
  stage_chunk((char*)sm.WB[0], w0base, t);  // A = W0h0(0)
  stage_chunk((char*)sm.WB[1], w1base, t);  // B = W1k0(0)

  // ---- gather: 2 threads/query, 16 feats each; lat -> NET head (80B rows) ----
  {
    const int q = t >> 1, s = t & 1;
    const int qg = qbase + q;
    float acc[16];
#pragma unroll
    for (int e = 0; e < 16; ++e) acc[e] = 0.f;
    if (qg < nq) {
      const float qx = query[qg * 3 + 0];
      const float qy = query[qg * 3 + 1];
      const float qz = query[qg * 3 + 2];
      const float fx = floorf(qx), fy = floorf(qy), fz = floorf(qz);
      const float rx = qx - fx, ry = qy - fy, rz = qz - fz;
      const int bx = (int)fx, by = (int)fy, bz = (int)fz;
      const float wx[2] = {1.f - rx, rx}, wy[2] = {1.f - ry, ry},
                  wz[2] = {1.f - rz, rz};
#pragma unroll
      for (int c = 0; c < 8; ++c) {
        const int ox = (c >> 2) & 1, oy = (c >> 1) & 1, oz = c & 1;
        const float wgt = wx[ox] * wy[oy] * wz[oz];
        const float* f = z_feats +
                         (size_t)(((bx + ox) * GR + (by + oy)) * GR + (bz + oz)) * ZD +
                         s * 16;
#pragma unroll
        for (int v4 = 0; v4 < 4; ++v4) {
          const float4 v = *(const float4*)(f + v4 * 4);
          acc[v4 * 4 + 0] = fmaf(wgt, v.x, acc[v4 * 4 + 0]);
          acc[v4 * 4 + 1] = fmaf(wgt, v.y, acc[v4 * 4 + 1]);
          acc[v4 * 4 + 2] = fmaf(wgt, v.z, acc[v4 * 4 + 2]);
          acc[v4 * 4 + 3] = fmaf(wgt, v.w, acc[v4 * 4 + 3]);
        }
      }
    }
    f16x8 h0, h1;
#pragma unroll
    for (int e = 0; e < 8; ++e) {
      h0[e] = (_Float16)acc[e];
      h1[e] = (_Float16)acc[8 + e];
    }
    char* lb = (char*)sm.NET + q * 80 + s * 32;
    *(f16x8*)lb = h0;
    *(f16x8*)(lb + 16) = h1;
  }
  __syncthreads();  // bar0: lat visible; prologue chunks drained

  // ---- latf (persist) + fc_p ----
  f16x8 latf[4];
#pragma unroll
  for (int qt = 0; qt < 4; ++qt)
    latf[qt] =
        *(const f16x8*)((const char*)sm.NET + (q0 + 16 * qt + lr) * 80 + lg * 16);

  f32x4 acc[4][4];
#pragma unroll
  for (int jt = 0; jt < 4; ++jt) {
    const f32x4 bv = *(const f32x4*)(fc_p_b + j0 + 16 * jt + 4 * lg);
#pragma unroll
    for (int qt = 0; qt < 4; ++qt) acc[jt][qt] = bv;
  }
#pragma unroll
  for (int jt = 0; jt < 4; ++jt) {
    const f16x8 wf = *(const f16x8*)(ws + OFF_P + (j0 + 16 * jt + lr) * 32 + lg * 8);
#pragma unroll
    for (int qt = 0; qt < 4; ++qt)
      acc[jt][qt] = __builtin_amdgcn_mfma_f32_16x16x32_f16(wf, latf[qt], acc[jt][qt],
                                                           0, 0, 0);
  }

#pragma unroll 1
  for (int i = 0; i < NBLK; ++i) {
    // ---- P0: fc_c (direct-global frags) + bias; write relu(net) -> NET ----
#pragma unroll
    for (int jt = 0; jt < 4; ++jt) {
      const f16x8 wf =
          *(const f16x8*)(ws + OFF_C + i * 4096 + (j0 + 16 * jt + lr) * 32 + lg * 8);
#pragma unroll
      for (int qt = 0; qt < 4; ++qt)
        acc[jt][qt] = __builtin_amdgcn_mfma_f32_16x16x32_f16(wf, latf[qt],
                                                             acc[jt][qt], 0, 0, 0);
      const f32x4 bv = *(const f32x4*)(fc_c_b + i * HD + j0 + 16 * jt + 4 * lg);
#pragma unroll
      for (int qt = 0; qt < 4; ++qt) acc[jt][qt] += bv;
    }
#pragma unroll
    for (int jt = 0; jt < 4; ++jt)
#pragma unroll
      for (int qt = 0; qt < 4; ++qt) {
        const int q = q0 + 16 * qt + lr;
        const int G = ((j0 >> 3) + 2 * jt + (lg >> 1)) ^ (q & 7);
        *(f16x4*)((char*)sm.NET + q * 256 + (G << 4) + ((lg & 1) << 3)) =
            relu_pack(acc[jt][qt]);
      }
    __syncthreads();  // bar1: NET ready; prev-iter P4 readers of B done

    if (i > 0) stage_chunk((char*)sm.WB[1], w1base + i * 32768, t);  // B<-W1k0(i)
    // ---- P1: h0 = relu(NET) @ W0h0 (slot A) ----
    fc0_half(sm, 0, fc0_b + i * HD, qe, lr, lg);
    __syncthreads();  // bar2: H(k0) ready; A readers done

    stage_chunk((char*)sm.WB[0], w0base + i * 32768 + 16384, t);  // A<-W0h1(i)
    // ---- P2: dx += H @ W1k0 (slot B) ----
    fc1_half(sm, 1, acc, j0, q0, lr, lg);
    __syncthreads();  // bar3: H(k0) reads done; B readers done

    stage_chunk((char*)sm.WB[1], w1base + i * 32768 + 16384, t);  // B<-W1k1(i)
    // ---- P3: h1 = relu(NET) @ W0h1 (slot A) ----
    fc0_half(sm, 2 - 2, fc0_b + i * HD + 64, qe, lr, lg);  // slot A (=0)
    __syncthreads();  // bar4: H(k1) ready; A readers done; NET readers done

    if (i + 1 < NBLK)
      stage_chunk((char*)sm.WB[0], w0base + (i + 1) * 32768, t);  // A<-W0h0(i+1)
    // ---- P4: dx += H @ W1k1 (slot B) ; net += b1 ----
    fc1_half(sm, 1, acc, j0, q0, lr, lg);
#pragma unroll
    for (int jt = 0; jt < 4; ++jt) {
      const f32x4 bv = *(const f32x4*)(fc1_b + i * HD + j0 + 16 * jt + 4 * lg);
#pragma unroll
      for (int qt = 0; qt < 4; ++qt) acc[jt][qt] += bv;
    }
    // no barrier: P0(i+1) writes NET, whose last readers (P3) retired at bar4
  }
  __syncthreads();  // final: H readers (P4) done; H reusable as reduce scratch

  // ---- epilogue: out[q] = leaky(net) . wout + b ----
  float* red = (float*)sm.H;  // [2][128] f32 partials
  {
    float p[4];
#pragma unroll
    for (int qt = 0; qt < 4; ++qt) p[qt] = 0.f;
#pragma unroll
    for (int jt = 0; jt < 4; ++jt) {
      const f32x4 wv = *(const f32x4*)(fc_out_w + j0 + 16 * jt + 4 * lg);
#pragma unroll
      for (int qt = 0; qt < 4; ++qt) {
        const f32x4 a = acc[jt][qt];
#pragma unroll
        for (int r = 0; r < 4; ++r) {
          const float v = (a[r] > 0.f) ? a[r] : 0.2f * a[r];
          p[qt] = fmaf(v, wv[r], p[qt]);
        }
      }
    }
#pragma unroll
    for (int qt = 0; qt < 4; ++qt) {
      p[qt] += __shfl_xor(p[qt], 16);
      p[qt] += __shfl_xor(p[qt], 32);
    }
    if (lg == 0) {
#pragma unroll
      for (int qt = 0; qt < 4; ++qt)
        red[(w & 1) * TQ + q0 + 16 * qt + lr] = p[qt];
    }
  }
  __syncthreads();
  if (t < TQ) {
    const int qg = qbase + t;
    if (qg < nq) out[qg] = red[t] + red[TQ + t] + fc_out_b[0];
  }
}

extern "C" void kernel_launch(void* const* d_in, const int* in_sizes, int n_in,
                              void* d_out, int out_size, void* d_ws,
                              size_t ws_size, hipStream_t stream) {
  const float* z_feats = (const float*)d_in[0];
  const float* query = (const float*)d_in[1];
  const float* fc_p_w = (const float*)d_in[2];
  const float* fc_p_b = (const float*)d_in[3];
  const float* fc_c_w = (const float*)d_in[4];
  const float* fc_c_b = (const float*)d_in[5];
  const float* fc0_w = (const float*)d_in[6];
  const float* fc0_b = (const float*)d_in[7];
  const float* fc1_w = (const float*)d_in[8];
  const float* fc1_b = (const float*)d_in[9];
  const float* fc_out_w = (const float*)d_in[10];
  const float* fc_out_b = (const float*)d_in[11];
  float* out = (float*)d_out;
  _Float16* ws = (_Float16*)d_ws;

  const int nq = in_sizes[1] / 3;

  convert_weights<<<(WS_HALVES + 255) / 256, 256, 0, stream>>>(fc_p_w, fc_c_w,
                                                               fc0_w, fc1_w, ws);
  const int grid = (nq + TQ - 1) / TQ;
  patch_decoder_kernel<<<grid, BLOCK, 0, stream>>>(z_feats, query, ws, fc_p_b,
                                                   fc_c_b, fc0_b, fc1_b, fc_out_w,
                                                   fc_out_b, out, nq);
}